// Round 8
// baseline (141.556 us; speedup 1.0000x reference)
//
#include <hip/hip_runtime.h>
#include <hip/hip_bf16.h>
#include <math.h>

// Problem constants (B,C_IN,C_OUT,STYLE,H,W = 4,128,128,512,64,64)
#define NN 4096
#define EPSV 1e-5f

typedef short short8 __attribute__((ext_vector_type(8)));   // 8 bf16 bit-patterns
typedef float f32x4 __attribute__((ext_vector_type(4)));

// ---- workspace layout (float offsets) ----
static constexpr size_t OFF_SCALE = 0;                            // [4*128]
static constexpr size_t OFF_BIAS  = 512;                          // [4*128]
static constexpr size_t OFF_H     = 1024;                         // [4*128*4096] f32
static constexpr size_t OFF_Q     = OFF_H  + (size_t)4*128*4096;  // [4*16*4096]
static constexpr size_t OFF_K     = OFF_Q  + (size_t)4*16*4096;
static constexpr size_t OFF_V     = OFF_K  + (size_t)4*16*4096;   // [4*128*4096]
static constexpr size_t OFF_AO    = OFF_V  + (size_t)4*128*4096;  // [4*128*4096]
// bf16 regions (ushort), sizes given in float units (/2)
static constexpr size_t OFF_XHI   = OFF_AO + (size_t)4*128*4096;            // 4*66*66*128 us
static constexpr size_t OFF_XLO   = OFF_XHI + (size_t)4*66*66*128/2;
static constexpr size_t OFF_WPK   = OFF_XLO + (size_t)4*66*66*128/2;        // 2*4*9*8*64*8 us

__device__ __forceinline__ unsigned short f2bf(float f) {   // RNE to bf16 bits
    unsigned u = __float_as_uint(f);
    unsigned r = u + 0x7FFFu + ((u >> 16) & 1u);
    return (unsigned short)(r >> 16);
}
__device__ __forceinline__ float bf2f(unsigned short h) {
    return __uint_as_float(((unsigned)h) << 16);
}

// ---------------------------------------------------------------------------
// prep: ONE launch doing (a) x transpose+pad+bf16 split, (b) weight pack,
// (c) style GEMV. Role by blockIdx.x:
//   [0,528):   xpose half — yp=bi>>3, b=(bi&7)>>1, h=bi&1 (ci half)
//   [528,672): wpack — 4 ids per block
//   [672,800): style — 4 (b,c) rows per block
// ---------------------------------------------------------------------------
__global__ __launch_bounds__(256)
void prep(const float* __restrict__ x, const float* __restrict__ conv_w,
          const float* __restrict__ style,
          const float* __restrict__ ss_w, const float* __restrict__ ss_b,
          const float* __restrict__ sb_w, const float* __restrict__ sb_b,
          float* __restrict__ ws) {
    const int bi = blockIdx.x;
    const int t  = threadIdx.x;

    if (bi < 528) {
        // ---------------- xpose: (yp, b, ci-half) ----------------
        const int yp = bi >> 3;
        const int b  = (bi & 7) >> 1;
        const int h  = bi & 1;                 // ci in [h*64, h*64+64)
        unsigned short* xh = (unsigned short*)(ws + OFF_XHI) + ((size_t)b * 66 + yp) * 66 * 128;
        unsigned short* xl = (unsigned short*)(ws + OFF_XLO) + ((size_t)b * 66 + yp) * 66 * 128;
        const short8 z8 = {0,0,0,0,0,0,0,0};

        if (yp == 0 || yp == 65) {             // full zero row (this ci-half)
            for (int task = t; task < 1056; task += 256) {
                const int buf = task >= 528;
                const int tt  = task - 528 * buf;
                const int xp  = tt >> 3, g = tt & 7;
                unsigned short* p = (buf ? xl : xh) + (size_t)xp * 128 + h * 64 + g * 8;
                *(short8*)p = z8;
            }
            return;
        }
        const int y = yp - 1;
        __shared__ float s[64][65];
        const float* src = x + (size_t)b * 128 * NN + (size_t)h * 64 * NN + y * 64;
        for (int j = t; j < 4096; j += 256) {  // coalesced [ci][xx] read
            const int ci = j >> 6, xx = j & 63;
            s[xx][ci] = src[(size_t)ci * NN + xx];
        }
        if (t < 32) {                          // zero xp=0 / xp=65 edges
            const int buf = t >> 4, e = (t >> 3) & 1, g = t & 7;
            unsigned short* p = (buf ? xl : xh) + (size_t)e * 65 * 128 + h * 64 + g * 8;
            *(short8*)p = z8;
        }
        __syncthreads();
        #pragma unroll
        for (int rep = 0; rep < 2; ++rep) {
            const int task = t + rep * 256;    // 512 tasks: 64 xx * 8 groups
            const int xx = task >> 3, g = task & 7;
            short8 vh, vl;
            #pragma unroll
            for (int j = 0; j < 8; ++j) {
                const float f = s[xx][g * 8 + j];
                const unsigned short hh = f2bf(f);
                vh[j] = (short)hh;
                vl[j] = (short)f2bf(f - bf2f(hh));
            }
            const size_t o = (size_t)(xx + 1) * 128 + h * 64 + g * 8;
            *(short8*)(xh + o) = vh;
            *(short8*)(xl + o) = vl;
        }
    } else if (bi < 672) {
        // ---------------- wpack: B-fragment pre-pack ----------------
        const int id = (bi - 528) * 4 + (t >> 6);    // 0..575
        const int l  = t & 63;
        const int cog = id & 7;
        const int q   = id >> 3;
        const int tap = q % 9;
        const int p2  = q / 9;
        const int kb  = p2 & 3;
        const int part= p2 >> 2;
        const int co  = cog * 16 + (l & 15);
        const int ci0 = kb * 32 + (l >> 4) * 8;
        short8 v;
        #pragma unroll
        for (int j = 0; j < 8; ++j) {
            const float f = conv_w[(size_t)co * 1152 + (size_t)(ci0 + j) * 9 + tap];
            const unsigned short hh = f2bf(f);
            v[j] = (short)(part == 0 ? hh : f2bf(f - bf2f(hh)));
        }
        unsigned short* wp = (unsigned short*)(ws + OFF_WPK);
        *(short8*)(wp + ((size_t)id * 64 + l) * 8) = v;
    } else {
        // ---------------- style GEMV ----------------
        const int bc = (bi - 672) * 4 + (t >> 6);    // 0..511
        const int b = bc >> 7, c = bc & 127;
        const int lane = t & 63;
        const float* st = style + (size_t)b * 512;
        float s1 = 0.f, s2 = 0.f;
        for (int e = lane; e < 512; e += 64) {
            const float sv = st[e];
            s1 = fmaf(sv, ss_w[(size_t)c * 512 + e], s1);
            s2 = fmaf(sv, sb_w[(size_t)c * 512 + e], s2);
        }
        #pragma unroll
        for (int off = 32; off; off >>= 1) {
            s1 += __shfl_xor(s1, off);
            s2 += __shfl_xor(s2, off);
        }
        if (lane == 0) {
            ws[OFF_SCALE + bc] = s1 + ss_b[c];
            ws[OFF_BIAS  + bc] = s2 + sb_b[c];
        }
    }
}

// ---------------------------------------------------------------------------
// mfma_conv: conv3x3 + bias + AdaIN -> h.
// In-block K-split: 8 waves; waves 0-3 (khalf=0) do kb{0,1}, waves 4-7 do
// kb{2,3} — 18 stages each (half the serial latency chain), combined via a
// 16KB LDS exchange + ONE barrier. Grid 512 = 2 blocks/CU = 4 waves/SIMD.
// 6-deep software pipeline, static stage indexing; __launch_bounds__(512,2)
// sets scheduler pressure target to 2 waves/EU so the ~230 live VGPRs are NOT
// sunk (4 resident waves x 230 regs << 2048/SIMD file).
// ---------------------------------------------------------------------------
struct St { short8 ah0, ah1, al0, al1, bh0, bh1, bl0, bl1; };

__global__ __launch_bounds__(512, 2)
void mfma_conv(float* __restrict__ ws, const float* __restrict__ conv_b) {
    const int y   = blockIdx.x;
    const int coh = blockIdx.y;
    const int b   = blockIdx.z;
    const int t   = threadIdx.x;
    const int l   = t & 63;
    const int wv  = t >> 6;          // 0..7
    const int wsub = wv & 3;
    const int khalf = wv >> 2;       // 0: kb 0,1   1: kb 2,3
    const int wm  = wsub & 1;
    const int wn  = wsub >> 1;
    const int x0  = wm * 32;
    const int cobase = coh * 64 + wn * 32;
    const int lr = l & 15, lg = l >> 4;

    __shared__ float s_red[4][4][4][64];   // [wsub][frag][elem][lane] 16 KB

    const unsigned short* xh = (const unsigned short*)(ws + OFF_XHI)
                             + (size_t)b * 66 * 66 * 128 + (size_t)khalf * 64;
    const unsigned short* xl = (const unsigned short*)(ws + OFF_XLO)
                             + (size_t)b * 66 * 66 * 128 + (size_t)khalf * 64;
    // B-frag base for this thread: absolute stage = khalf*18 + local
    const unsigned short* wpb = (const unsigned short*)(ws + OFF_WPK)
                              + ((size_t)(khalf * 18) * 8 + (coh * 4 + wn * 2)) * 512
                              + (size_t)l * 8;

    const size_t aL0 = (size_t)(x0 + lr) * 128 + (size_t)lg * 8;  // ushort units
    const size_t aL1 = aL0 + 16 * 128;

    f32x4 acc00 = {0,0,0,0}, acc01 = {0,0,0,0};
    f32x4 acc10 = {0,0,0,0}, acc11 = {0,0,0,0};

    // local stage s in [0,18): kbl = s/9 (0/1 within half), tap = s%9
    auto load_st = [&](St& S, int s) {
        const int kbl = s / 9;                 // folds after unroll
        const int tap = s - 9 * kbl;
        const int ky  = tap / 3;
        const int kx  = tap - 3 * ky;
        const size_t su = ((size_t)(y + ky) * 66 + kx) * 128 + (size_t)kbl * 32;
        S.ah0 = *(const short8*)(xh + su + aL0);
        S.ah1 = *(const short8*)(xh + su + aL1);
        S.al0 = *(const short8*)(xl + su + aL0);
        S.al1 = *(const short8*)(xl + su + aL1);
        const unsigned short* pbh = wpb + (size_t)s * 4096;        // 8*512
        const unsigned short* pbl = pbh + (size_t)36 * 4096;       // part=1 region
        S.bh0 = *(const short8*)pbh;
        S.bh1 = *(const short8*)(pbh + 512);
        S.bl0 = *(const short8*)pbl;
        S.bl1 = *(const short8*)(pbl + 512);
    };
    auto do_mfma = [&](const St& S) {
        acc00 = __builtin_amdgcn_mfma_f32_16x16x32_bf16(S.ah0, S.bh0, acc00, 0,0,0);
        acc01 = __builtin_amdgcn_mfma_f32_16x16x32_bf16(S.ah0, S.bh1, acc01, 0,0,0);
        acc10 = __builtin_amdgcn_mfma_f32_16x16x32_bf16(S.ah1, S.bh0, acc10, 0,0,0);
        acc11 = __builtin_amdgcn_mfma_f32_16x16x32_bf16(S.ah1, S.bh1, acc11, 0,0,0);
        acc00 = __builtin_amdgcn_mfma_f32_16x16x32_bf16(S.al0, S.bh0, acc00, 0,0,0);
        acc01 = __builtin_amdgcn_mfma_f32_16x16x32_bf16(S.al0, S.bh1, acc01, 0,0,0);
        acc10 = __builtin_amdgcn_mfma_f32_16x16x32_bf16(S.al1, S.bh0, acc10, 0,0,0);
        acc11 = __builtin_amdgcn_mfma_f32_16x16x32_bf16(S.al1, S.bh1, acc11, 0,0,0);
        acc00 = __builtin_amdgcn_mfma_f32_16x16x32_bf16(S.ah0, S.bl0, acc00, 0,0,0);
        acc01 = __builtin_amdgcn_mfma_f32_16x16x32_bf16(S.ah0, S.bl1, acc01, 0,0,0);
        acc10 = __builtin_amdgcn_mfma_f32_16x16x32_bf16(S.ah1, S.bl0, acc10, 0,0,0);
        acc11 = __builtin_amdgcn_mfma_f32_16x16x32_bf16(S.ah1, S.bl1, acc11, 0,0,0);
    };

    St S[6];
    #pragma unroll
    for (int i = 0; i < 6; ++i) load_st(S[i], i);
    #pragma unroll
    for (int ss = 6; ss < 18; ss += 6) {
        #pragma unroll
        for (int i = 0; i < 6; ++i) { do_mfma(S[i]); load_st(S[i], ss + i); }
    }
    #pragma unroll
    for (int i = 0; i < 6; ++i) do_mfma(S[i]);

    // ---- cross-half reduction: khalf=1 publishes, khalf=0 combines ----
    if (khalf == 1) {
        #pragma unroll
        for (int e = 0; e < 4; ++e) {
            s_red[wsub][0][e][l] = acc00[e];
            s_red[wsub][1][e][l] = acc01[e];
            s_red[wsub][2][e][l] = acc10[e];
            s_red[wsub][3][e][l] = acc11[e];
        }
    }
    __syncthreads();
    if (khalf == 1) return;
    #pragma unroll
    for (int e = 0; e < 4; ++e) {
        acc00[e] += s_red[wsub][0][e][l];
        acc01[e] += s_red[wsub][1][e][l];
        acc10[e] += s_red[wsub][2][e][l];
        acc11[e] += s_red[wsub][3][e][l];
    }

    // ---- epilogue: C/D layout col=lane&15 (co), row=(lane>>4)*4+reg (x) ----
    const float* scp = ws + OFF_SCALE + b * 128;
    const float* bip = ws + OFF_BIAS  + b * 128;
    float* hout = ws + OFF_H;
    #pragma unroll
    for (int nf = 0; nf < 2; ++nf) {
        const int co = cobase + nf * 16 + lr;
        const float sc = 1.f + scp[co];
        const float bi = bip[co];
        const float cb = conv_b[co];
        #pragma unroll
        for (int mf = 0; mf < 2; ++mf) {
            f32x4 a = (nf == 0) ? (mf == 0 ? acc00 : acc10)
                                : (mf == 0 ? acc01 : acc11);
            float4 o;
            o.x = (a[0] + cb) * sc + bi;
            o.y = (a[1] + cb) * sc + bi;
            o.z = (a[2] + cb) * sc + bi;
            o.w = (a[3] + cb) * sc + bi;
            const int xo = x0 + mf * 16 + lg * 4;
            *(float4*)(hout + (size_t)(b * 128 + co) * NN + y * 64 + xo) = o;
        }
    }
}

// ---------------------------------------------------------------------------
// qkv (runs only if gamma != 0): q/k/v 1x1 convs from h.
// ---------------------------------------------------------------------------
__global__ __launch_bounds__(256)
void qkv_kernel(float* __restrict__ ws,
                const float* __restrict__ qw, const float* __restrict__ qb,
                const float* __restrict__ kw, const float* __restrict__ kb,
                const float* __restrict__ vw, const float* __restrict__ vb,
                const float* __restrict__ gamma) {
    if (gamma[0] == 0.f) return;
    const int b  = blockIdx.y;
    const int oc = blockIdx.x;   // 0..159: 16 q, 16 k, 128 v
    const float* wrow; float bias; float* dst;
    if (oc < 16)      { wrow = qw + (size_t)oc * 128;        bias = qb[oc];
                        dst = ws + OFF_Q + (size_t)(b * 16 + oc) * NN; }
    else if (oc < 32) { int c = oc - 16; wrow = kw + (size_t)c * 128; bias = kb[c];
                        dst = ws + OFF_K + (size_t)(b * 16 + c) * NN; }
    else              { int c = oc - 32; wrow = vw + (size_t)c * 128; bias = vb[c];
                        dst = ws + OFF_V + (size_t)(b * 128 + c) * NN; }
    const float* hb = ws + OFF_H + (size_t)b * 128 * NN;
    for (int n = threadIdx.x; n < NN; n += 256) {
        float a = bias;
        for (int ci = 0; ci < 128; ++ci) a += hb[(size_t)ci * NN + n] * wrow[ci];
        dst[n] = a;
    }
}

// ---------------------------------------------------------------------------
// attn (runs only if gamma != 0): flash-style, 64 queries per block.
// ---------------------------------------------------------------------------
__global__ __launch_bounds__(256)
void attn_kernel(float* __restrict__ ws, const float* __restrict__ gamma) {
    if (gamma[0] == 0.f) return;
    const int b  = blockIdx.y;
    const int n0 = blockIdx.x * 64;
    const int t  = threadIdx.x;

    __shared__ float q_s[16][64];
    __shared__ float k_s[16][64];
    __shared__ float v_s[64][129];
    __shared__ float p_s[64][65];
    __shared__ float m_run[64], l_run[64], sc_s[64];

    const float* qp = ws + OFF_Q + (size_t)b * 16 * NN;
    const float* kp = ws + OFF_K + (size_t)b * 16 * NN;
    const float* vp = ws + OFF_V + (size_t)b * 128 * NN;

    for (int idx = t; idx < 16 * 64; idx += 256) {
        int cq = idx >> 6, j = idx & 63;
        q_s[cq][j] = qp[(size_t)cq * NN + n0 + j];
    }
    if (t < 64) { m_run[t] = -1e30f; l_run[t] = 0.f; }

    const int n  = t & 63;
    const int cg = t >> 6;
    float acc[32];
    #pragma unroll
    for (int i = 0; i < 32; ++i) acc[i] = 0.f;
    __syncthreads();

    for (int mt = 0; mt < 64; ++mt) {
        const int m0 = mt * 64;
        for (int idx = t; idx < 16 * 64; idx += 256) {
            int cq = idx >> 6, j = idx & 63;
            k_s[cq][j] = kp[(size_t)cq * NN + m0 + j];
        }
        for (int idx = t; idx < 128 * 64; idx += 256) {
            int c = idx >> 6, j = idx & 63;
            v_s[j][c] = vp[(size_t)c * NN + m0 + j];
        }
        __syncthreads();
        {
            const int nn2   = t & 63;
            const int mbase = (t >> 6) * 16;
            for (int mi = 0; mi < 16; ++mi) {
                const int mm = mbase + mi;
                float s = 0.f;
                #pragma unroll
                for (int cq = 0; cq < 16; ++cq) s += q_s[cq][nn2] * k_s[cq][mm];
                p_s[nn2][mm] = s;
            }
        }
        __syncthreads();
        if (t < 64) {
            float mold = m_run[t];
            float mx = mold;
            for (int mm = 0; mm < 64; ++mm) mx = fmaxf(mx, p_s[t][mm]);
            float sc = expf(mold - mx);
            float rs = 0.f;
            for (int mm = 0; mm < 64; ++mm) {
                float p = expf(p_s[t][mm] - mx);
                p_s[t][mm] = p;
                rs += p;
            }
            l_run[t] = l_run[t] * sc + rs;
            m_run[t] = mx;
            sc_s[t]  = sc;
        }
        __syncthreads();
        {
            const float sc = sc_s[n];
            #pragma unroll
            for (int i = 0; i < 32; ++i) acc[i] *= sc;
            for (int mm = 0; mm < 64; ++mm) {
                const float p = p_s[n][mm];
                #pragma unroll
                for (int i = 0; i < 32; ++i) acc[i] += p * v_s[mm][cg * 32 + i];
            }
        }
        __syncthreads();
    }

    const float inv = 1.f / l_run[n];
    float* ao = ws + OFF_AO + (size_t)b * 128 * NN;
    for (int i = 0; i < 32; ++i)
        ao[(size_t)(cg * 32 + i) * NN + n0 + n] = acc[i] * inv;
}

// ---------------------------------------------------------------------------
// h2 = gamma*attn_out + h; InstanceNorm (biased var, eps=1e-5); LeakyReLU.
// ---------------------------------------------------------------------------
__global__ __launch_bounds__(256)
void inorm_lrelu(const float* __restrict__ ws,
                 const float* __restrict__ gamma,
                 float* __restrict__ out) {
    const int bc = blockIdx.x;      // b*128 + c
    const int t  = threadIdx.x;
    const float g = gamma[0];

    const float4* hp = (const float4*)(ws + OFF_H  + (size_t)bc * NN);
    const float4* ap = (const float4*)(ws + OFF_AO + (size_t)bc * NN);

    float4 v[4];
    #pragma unroll
    for (int i = 0; i < 4; ++i) {
        float4 hv = hp[t + 256 * i];
        if (g != 0.f) {
            float4 av = ap[t + 256 * i];
            hv.x += g * av.x; hv.y += g * av.y; hv.z += g * av.z; hv.w += g * av.w;
        }
        v[i] = hv;
    }

    float s1 = 0.f, s2 = 0.f;
    #pragma unroll
    for (int i = 0; i < 4; ++i) {
        s1 += v[i].x + v[i].y + v[i].z + v[i].w;
        s2 += v[i].x * v[i].x + v[i].y * v[i].y + v[i].z * v[i].z + v[i].w * v[i].w;
    }
    #pragma unroll
    for (int off = 32; off; off >>= 1) {
        s1 += __shfl_xor(s1, off);
        s2 += __shfl_xor(s2, off);
    }
    __shared__ float r1[4], r2[4];
    if ((t & 63) == 0) { r1[t >> 6] = s1; r2[t >> 6] = s2; }
    __syncthreads();
    const float S1 = r1[0] + r1[1] + r1[2] + r1[3];
    const float S2 = r2[0] + r2[1] + r2[2] + r2[3];
    const float mu  = S1 * (1.f / 4096.f);
    const float var = S2 * (1.f / 4096.f) - mu * mu;
    const float rs  = 1.f / sqrtf(var + EPSV);

    float4* op = (float4*)out + (size_t)bc * (NN / 4);
    #pragma unroll
    for (int i = 0; i < 4; ++i) {
        float4 o;
        o.x = (v[i].x - mu) * rs; o.x = o.x >= 0.f ? o.x : 0.2f * o.x;
        o.y = (v[i].y - mu) * rs; o.y = o.y >= 0.f ? o.y : 0.2f * o.y;
        o.z = (v[i].z - mu) * rs; o.z = o.z >= 0.f ? o.z : 0.2f * o.z;
        o.w = (v[i].w - mu) * rs; o.w = o.w >= 0.f ? o.w : 0.2f * o.w;
        op[t + 256 * i] = o;
    }
}

// ---------------------------------------------------------------------------
extern "C" void kernel_launch(void* const* d_in, const int* in_sizes, int n_in,
                              void* d_out, int out_size, void* d_ws, size_t ws_size,
                              hipStream_t stream) {
    const float* x      = (const float*)d_in[0];
    const float* style  = (const float*)d_in[1];
    const float* conv_w = (const float*)d_in[2];
    const float* conv_b = (const float*)d_in[3];
    const float* ss_w   = (const float*)d_in[4];
    const float* ss_b   = (const float*)d_in[5];
    const float* sb_w   = (const float*)d_in[6];
    const float* sb_b   = (const float*)d_in[7];
    const float* q_w    = (const float*)d_in[8];
    const float* q_b    = (const float*)d_in[9];
    const float* k_w    = (const float*)d_in[10];
    const float* k_b    = (const float*)d_in[11];
    const float* v_w    = (const float*)d_in[12];
    const float* v_b    = (const float*)d_in[13];
    const float* gamma  = (const float*)d_in[14];
    float* ws  = (float*)d_ws;
    float* out = (float*)d_out;

    prep<<<800, 256, 0, stream>>>(x, conv_w, style, ss_w, ss_b, sb_w, sb_b, ws);
    mfma_conv<<<dim3(64, 2, 4), 512, 0, stream>>>(ws, conv_b);
    qkv_kernel<<<dim3(160, 4), 256, 0, stream>>>(ws, q_w, q_b, k_w, k_b, v_w, v_b, gamma);
    attn_kernel<<<dim3(64, 4), 256, 0, stream>>>(ws, gamma);
    inorm_lrelu<<<512, 256, 0, stream>>>(ws, gamma, out);
}

// Round 9
// 123.854 us; speedup vs baseline: 1.1429x; 1.1429x over previous
//
#include <hip/hip_runtime.h>
#include <hip/hip_bf16.h>
#include <math.h>

// Problem constants (B,C_IN,C_OUT,STYLE,H,W = 4,128,128,512,64,64)
#define NN 4096
#define EPSV 1e-5f

typedef short short8 __attribute__((ext_vector_type(8)));   // 8 bf16 bit-patterns
typedef float f32x4 __attribute__((ext_vector_type(4)));

// ---- workspace layout (float offsets) ----
static constexpr size_t OFF_SCALE = 0;                            // [4*128]
static constexpr size_t OFF_BIAS  = 512;                          // [4*128]
static constexpr size_t OFF_H     = 1024;                         // h partial kh=0
static constexpr size_t OFF_Q     = OFF_H  + (size_t)4*128*4096;  // [4*16*4096]
static constexpr size_t OFF_K     = OFF_Q  + (size_t)4*16*4096;
static constexpr size_t OFF_V     = OFF_K  + (size_t)4*16*4096;   // [4*128*4096]
static constexpr size_t OFF_AO    = OFF_V  + (size_t)4*128*4096;  // [4*128*4096]
// bf16 regions (ushort), sizes given in float units (/2)
static constexpr size_t OFF_XHI   = OFF_AO + (size_t)4*128*4096;            // 4*66*66*128 us
static constexpr size_t OFF_XLO   = OFF_XHI + (size_t)4*66*66*128/2;
static constexpr size_t OFF_WPK   = OFF_XLO + (size_t)4*66*66*128/2;        // 2*36*8*64*8 us
static constexpr size_t OFF_H1    = OFF_WPK + (size_t)2*36*8*64*8/2;        // h partial kh=1

__device__ __forceinline__ unsigned short f2bf(float f) {   // RNE to bf16 bits
    unsigned u = __float_as_uint(f);
    unsigned r = u + 0x7FFFu + ((u >> 16) & 1u);
    return (unsigned short)(r >> 16);
}
__device__ __forceinline__ float bf2f(unsigned short h) {
    return __uint_as_float(((unsigned)h) << 16);
}

// ---------------------------------------------------------------------------
// prep: ONE launch doing (a) x transpose+pad+bf16 split, (b) weight pack,
// (c) style GEMV. Role by blockIdx.x (unchanged from r7/r8).
// ---------------------------------------------------------------------------
__global__ __launch_bounds__(256)
void prep(const float* __restrict__ x, const float* __restrict__ conv_w,
          const float* __restrict__ style,
          const float* __restrict__ ss_w, const float* __restrict__ ss_b,
          const float* __restrict__ sb_w, const float* __restrict__ sb_b,
          float* __restrict__ ws) {
    const int bi = blockIdx.x;
    const int t  = threadIdx.x;

    if (bi < 528) {
        const int yp = bi >> 3;
        const int b  = (bi & 7) >> 1;
        const int h  = bi & 1;                 // ci in [h*64, h*64+64)
        unsigned short* xh = (unsigned short*)(ws + OFF_XHI) + ((size_t)b * 66 + yp) * 66 * 128;
        unsigned short* xl = (unsigned short*)(ws + OFF_XLO) + ((size_t)b * 66 + yp) * 66 * 128;
        const short8 z8 = {0,0,0,0,0,0,0,0};

        if (yp == 0 || yp == 65) {             // full zero row (this ci-half)
            for (int task = t; task < 1056; task += 256) {
                const int buf = task >= 528;
                const int tt  = task - 528 * buf;
                const int xp  = tt >> 3, g = tt & 7;
                unsigned short* p = (buf ? xl : xh) + (size_t)xp * 128 + h * 64 + g * 8;
                *(short8*)p = z8;
            }
            return;
        }
        const int y = yp - 1;
        __shared__ float s[64][65];
        const float* src = x + (size_t)b * 128 * NN + (size_t)h * 64 * NN + y * 64;
        for (int j = t; j < 4096; j += 256) {
            const int ci = j >> 6, xx = j & 63;
            s[xx][ci] = src[(size_t)ci * NN + xx];
        }
        if (t < 32) {                          // zero xp=0 / xp=65 edges
            const int buf = t >> 4, e = (t >> 3) & 1, g = t & 7;
            unsigned short* p = (buf ? xl : xh) + (size_t)e * 65 * 128 + h * 64 + g * 8;
            *(short8*)p = z8;
        }
        __syncthreads();
        #pragma unroll
        for (int rep = 0; rep < 2; ++rep) {
            const int task = t + rep * 256;
            const int xx = task >> 3, g = task & 7;
            short8 vh, vl;
            #pragma unroll
            for (int j = 0; j < 8; ++j) {
                const float f = s[xx][g * 8 + j];
                const unsigned short hh = f2bf(f);
                vh[j] = (short)hh;
                vl[j] = (short)f2bf(f - bf2f(hh));
            }
            const size_t o = (size_t)(xx + 1) * 128 + h * 64 + g * 8;
            *(short8*)(xh + o) = vh;
            *(short8*)(xl + o) = vl;
        }
    } else if (bi < 672) {
        const int id = (bi - 528) * 4 + (t >> 6);    // 0..575
        const int l  = t & 63;
        const int cog = id & 7;
        const int q   = id >> 3;
        const int tap = q % 9;
        const int p2  = q / 9;
        const int kb  = p2 & 3;
        const int part= p2 >> 2;
        const int co  = cog * 16 + (l & 15);
        const int ci0 = kb * 32 + (l >> 4) * 8;
        short8 v;
        #pragma unroll
        for (int j = 0; j < 8; ++j) {
            const float f = conv_w[(size_t)co * 1152 + (size_t)(ci0 + j) * 9 + tap];
            const unsigned short hh = f2bf(f);
            v[j] = (short)(part == 0 ? hh : f2bf(f - bf2f(hh)));
        }
        unsigned short* wp = (unsigned short*)(ws + OFF_WPK);
        *(short8*)(wp + ((size_t)id * 64 + l) * 8) = v;
    } else {
        const int bc = (bi - 672) * 4 + (t >> 6);    // 0..511
        const int b = bc >> 7, c = bc & 127;
        const int lane = t & 63;
        const float* st = style + (size_t)b * 512;
        float s1 = 0.f, s2 = 0.f;
        for (int e = lane; e < 512; e += 64) {
            const float sv = st[e];
            s1 = fmaf(sv, ss_w[(size_t)c * 512 + e], s1);
            s2 = fmaf(sv, sb_w[(size_t)c * 512 + e], s2);
        }
        #pragma unroll
        for (int off = 32; off; off >>= 1) {
            s1 += __shfl_xor(s1, off);
            s2 += __shfl_xor(s2, off);
        }
        if (lane == 0) {
            ws[OFF_SCALE + bc] = s1 + ss_b[c];
            ws[OFF_BIAS  + bc] = s2 + sb_b[c];
        }
    }
}

// ---------------------------------------------------------------------------
// mfma_conv: LDS-tiled implicit-GEMM conv (m97-style structure).
// Grid (64 y, 4 b, 2 khalf) = 512 blocks x 256 thr (4 waves) = 2 blocks/CU.
// Per block: M=64 (row y), N=128 (all co), K = 18 stages of (kbl,tap)x32ci.
// Per stage: block stages 24 frag-tiles (A: 2part x 4mf, B: 2part x 8cog,
// 1KB each, fragment-ordered = lane-linear) into double-buffered LDS via
// reg-staging: global loads issued BEFORE compute (T14), ds_write after,
// ONE barrier per stage. All ds ops lane-linear -> conflict-free.
// Each wave wv: co-quarter cog0=2wv, 4 Mfrag x 2 Nfrag x 3 combos = 24 MFMA.
// Partial C (no affine) -> h0 / h1 by khalf; combine+affine in consumers.
// ---------------------------------------------------------------------------
struct Regs { short8 r[6]; };

__global__ __launch_bounds__(256)
void mfma_conv(float* __restrict__ ws) {
    const int y  = blockIdx.x;
    const int b  = blockIdx.y;
    const int kh = blockIdx.z;
    const int t  = threadIdx.x;
    const int l  = t & 63;
    const int wv = t >> 6;
    const int lr = l & 15, lg = l >> 4;

    __shared__ unsigned short smem[2 * 12288];   // 48 KB: [buf][frag 24][lane][8]

    const unsigned short* xh = (const unsigned short*)(ws + OFF_XHI) + (size_t)b * 66 * 66 * 128;
    const unsigned short* xl = (const unsigned short*)(ws + OFF_XLO) + (size_t)b * 66 * 66 * 128;
    const unsigned short* wpk = (const unsigned short*)(ws + OFF_WPK);

    // stage s (0..17): kbl = s>=9, tap = s-9*kbl, kb = kh*2+kbl
    auto loadR = [&](Regs& R, int s) {
        const int kbl = (s >= 9) ? 1 : 0;
        const int tap = s - 9 * kbl;
        const int ky  = tap / 3;
        const int kx  = tap - 3 * ky;
        const int kb  = kh * 2 + kbl;
        const int ci0 = kb * 32;
        #pragma unroll
        for (int i = 0; i < 6; ++i) {
            const int f = wv * 6 + i;
            if (f < 8) {            // A-frag: part=f>>2, mf=f&3 (wave-uniform)
                const int part = f >> 2, mf = f & 3;
                const unsigned short* xp = part ? xl : xh;
                const size_t src = ((size_t)((y + ky) * 66 + kx + mf * 16 + lr)) * 128
                                 + ci0 + lg * 8;
                R.r[i] = *(const short8*)(xp + src);
            } else {                // B-frag: g=f-8, part=g>>3, cog=g&7
                const int g = f - 8;
                const int part = g >> 3, cog = g & 7;
                const size_t src = ((size_t)(part * 36 + kb * 9 + tap) * 8 + cog) * 512
                                 + (size_t)l * 8;
                R.r[i] = *(const short8*)(wpk + src);
            }
        }
    };
    auto dsWrite = [&](int buf, const Regs& R) {
        unsigned short* dst = smem + buf * 12288 + (size_t)wv * 6 * 512 + l * 8;
        #pragma unroll
        for (int i = 0; i < 6; ++i)
            *(short8*)(dst + i * 512) = R.r[i];
    };

    f32x4 acc[4][2];
    #pragma unroll
    for (int mf = 0; mf < 4; ++mf)
        #pragma unroll
        for (int nf = 0; nf < 2; ++nf) acc[mf][nf] = (f32x4){0,0,0,0};

    const int cog0 = wv * 2;
    auto compute = [&](int buf) {
        const unsigned short* sb = smem + buf * 12288 + (size_t)l * 8;
        short8 bh0 = *(const short8*)(sb + (size_t)(8 + cog0) * 512);
        short8 bh1 = *(const short8*)(sb + (size_t)(9 + cog0) * 512);
        short8 bl0 = *(const short8*)(sb + (size_t)(16 + cog0) * 512);
        short8 bl1 = *(const short8*)(sb + (size_t)(17 + cog0) * 512);
        #pragma unroll
        for (int mf = 0; mf < 4; ++mf) {
            short8 ah = *(const short8*)(sb + (size_t)mf * 512);
            short8 al = *(const short8*)(sb + (size_t)(4 + mf) * 512);
            acc[mf][0] = __builtin_amdgcn_mfma_f32_16x16x32_bf16(ah, bh0, acc[mf][0], 0,0,0);
            acc[mf][1] = __builtin_amdgcn_mfma_f32_16x16x32_bf16(ah, bh1, acc[mf][1], 0,0,0);
            acc[mf][0] = __builtin_amdgcn_mfma_f32_16x16x32_bf16(al, bh0, acc[mf][0], 0,0,0);
            acc[mf][1] = __builtin_amdgcn_mfma_f32_16x16x32_bf16(al, bh1, acc[mf][1], 0,0,0);
            acc[mf][0] = __builtin_amdgcn_mfma_f32_16x16x32_bf16(ah, bl0, acc[mf][0], 0,0,0);
            acc[mf][1] = __builtin_amdgcn_mfma_f32_16x16x32_bf16(ah, bl1, acc[mf][1], 0,0,0);
        }
    };

    Regs RA, RB;
    // prologue: stage 0 -> buf0; RA <- stage 1
    loadR(RA, 0);
    dsWrite(0, RA);
    loadR(RA, 1);
    __syncthreads();

    for (int ss = 0; ss < 18; ss += 2) {
        // even stage ss (buf0); RA holds ss+1
        if (ss + 2 < 18) loadR(RB, ss + 2);      // issue early: hides under MFMA
        compute(0);
        dsWrite(1, RA);                          // stage ss+1 -> buf1
        __syncthreads();
        // odd stage ss+1 (buf1); RB holds ss+2
        if (ss + 3 < 18) loadR(RA, ss + 3);
        compute(1);
        if (ss + 2 < 18) dsWrite(0, RB);         // stage ss+2 -> buf0
        __syncthreads();
    }

    // ---- epilogue: raw partial sums (affine applied in consumers) ----
    float* hp = ws + (kh ? OFF_H1 : OFF_H);
    #pragma unroll
    for (int nf = 0; nf < 2; ++nf) {
        const int co = wv * 32 + nf * 16 + lr;
        #pragma unroll
        for (int mf = 0; mf < 4; ++mf) {
            f32x4 a = acc[mf][nf];
            float4 o; o.x = a[0]; o.y = a[1]; o.z = a[2]; o.w = a[3];
            *(float4*)(hp + (size_t)(b * 128 + co) * NN + y * 64 + mf * 16 + lg * 4) = o;
        }
    }
}

// ---------------------------------------------------------------------------
// qkv (runs only if gamma != 0): q/k/v 1x1 convs from modulated h0+h1.
// ---------------------------------------------------------------------------
__global__ __launch_bounds__(256)
void qkv_kernel(float* __restrict__ ws, const float* __restrict__ conv_b,
                const float* __restrict__ qw, const float* __restrict__ qb,
                const float* __restrict__ kw, const float* __restrict__ kb,
                const float* __restrict__ vw, const float* __restrict__ vb,
                const float* __restrict__ gamma) {
    if (gamma[0] == 0.f) return;
    const int b  = blockIdx.y;
    const int oc = blockIdx.x;   // 0..159: 16 q, 16 k, 128 v
    const int t  = threadIdx.x;
    __shared__ float aff[3][128];             // cb, sc, bi per channel
    if (t < 128) {
        aff[0][t] = conv_b[t];
        aff[1][t] = 1.f + ws[OFF_SCALE + b * 128 + t];
        aff[2][t] = ws[OFF_BIAS + b * 128 + t];
    }
    __syncthreads();
    const float* wrow; float bias; float* dst;
    if (oc < 16)      { wrow = qw + (size_t)oc * 128;        bias = qb[oc];
                        dst = ws + OFF_Q + (size_t)(b * 16 + oc) * NN; }
    else if (oc < 32) { int c = oc - 16; wrow = kw + (size_t)c * 128; bias = kb[c];
                        dst = ws + OFF_K + (size_t)(b * 16 + c) * NN; }
    else              { int c = oc - 32; wrow = vw + (size_t)c * 128; bias = vb[c];
                        dst = ws + OFF_V + (size_t)(b * 128 + c) * NN; }
    const float* h0 = ws + OFF_H  + (size_t)b * 128 * NN;
    const float* h1 = ws + OFF_H1 + (size_t)b * 128 * NN;
    for (int n = t; n < NN; n += 256) {
        float a = bias;
        for (int ci = 0; ci < 128; ++ci) {
            const float hm = (h0[(size_t)ci * NN + n] + h1[(size_t)ci * NN + n]
                              + aff[0][ci]) * aff[1][ci] + aff[2][ci];
            a += hm * wrow[ci];
        }
        dst[n] = a;
    }
}

// ---------------------------------------------------------------------------
// attn (runs only if gamma != 0): flash-style, 64 queries per block.
// ---------------------------------------------------------------------------
__global__ __launch_bounds__(256)
void attn_kernel(float* __restrict__ ws, const float* __restrict__ gamma) {
    if (gamma[0] == 0.f) return;
    const int b  = blockIdx.y;
    const int n0 = blockIdx.x * 64;
    const int t  = threadIdx.x;

    __shared__ float q_s[16][64];
    __shared__ float k_s[16][64];
    __shared__ float v_s[64][129];
    __shared__ float p_s[64][65];
    __shared__ float m_run[64], l_run[64], sc_s[64];

    const float* qp = ws + OFF_Q + (size_t)b * 16 * NN;
    const float* kp = ws + OFF_K + (size_t)b * 16 * NN;
    const float* vp = ws + OFF_V + (size_t)b * 128 * NN;

    for (int idx = t; idx < 16 * 64; idx += 256) {
        int cq = idx >> 6, j = idx & 63;
        q_s[cq][j] = qp[(size_t)cq * NN + n0 + j];
    }
    if (t < 64) { m_run[t] = -1e30f; l_run[t] = 0.f; }

    const int n  = t & 63;
    const int cg = t >> 6;
    float acc[32];
    #pragma unroll
    for (int i = 0; i < 32; ++i) acc[i] = 0.f;
    __syncthreads();

    for (int mt = 0; mt < 64; ++mt) {
        const int m0 = mt * 64;
        for (int idx = t; idx < 16 * 64; idx += 256) {
            int cq = idx >> 6, j = idx & 63;
            k_s[cq][j] = kp[(size_t)cq * NN + m0 + j];
        }
        for (int idx = t; idx < 128 * 64; idx += 256) {
            int c = idx >> 6, j = idx & 63;
            v_s[j][c] = vp[(size_t)c * NN + m0 + j];
        }
        __syncthreads();
        {
            const int nn2   = t & 63;
            const int mbase = (t >> 6) * 16;
            for (int mi = 0; mi < 16; ++mi) {
                const int mm = mbase + mi;
                float s = 0.f;
                #pragma unroll
                for (int cq = 0; cq < 16; ++cq) s += q_s[cq][nn2] * k_s[cq][mm];
                p_s[nn2][mm] = s;
            }
        }
        __syncthreads();
        if (t < 64) {
            float mold = m_run[t];
            float mx = mold;
            for (int mm = 0; mm < 64; ++mm) mx = fmaxf(mx, p_s[t][mm]);
            float sc = expf(mold - mx);
            float rs = 0.f;
            for (int mm = 0; mm < 64; ++mm) {
                float p = expf(p_s[t][mm] - mx);
                p_s[t][mm] = p;
                rs += p;
            }
            l_run[t] = l_run[t] * sc + rs;
            m_run[t] = mx;
            sc_s[t]  = sc;
        }
        __syncthreads();
        {
            const float sc = sc_s[n];
            #pragma unroll
            for (int i = 0; i < 32; ++i) acc[i] *= sc;
            for (int mm = 0; mm < 64; ++mm) {
                const float p = p_s[n][mm];
                #pragma unroll
                for (int i = 0; i < 32; ++i) acc[i] += p * v_s[mm][cg * 32 + i];
            }
        }
        __syncthreads();
    }

    const float inv = 1.f / l_run[n];
    float* ao = ws + OFF_AO + (size_t)b * 128 * NN;
    for (int i = 0; i < 32; ++i)
        ao[(size_t)(cg * 32 + i) * NN + n0 + n] = acc[i] * inv;
}

// ---------------------------------------------------------------------------
// inorm: h = ((h0+h1)+cb)*sc+bi (+ gamma*ao); InstanceNorm; LeakyReLU.
// ---------------------------------------------------------------------------
__global__ __launch_bounds__(256)
void inorm_lrelu(const float* __restrict__ ws, const float* __restrict__ conv_b,
                 const float* __restrict__ gamma, float* __restrict__ out) {
    const int bc = blockIdx.x;      // b*128 + c
    const int t  = threadIdx.x;
    const float g  = gamma[0];
    const float cb = conv_b[bc & 127];
    const float sc = 1.f + ws[OFF_SCALE + bc];
    const float bi = ws[OFF_BIAS  + bc];

    const float4* hp0 = (const float4*)(ws + OFF_H  + (size_t)bc * NN);
    const float4* hp1 = (const float4*)(ws + OFF_H1 + (size_t)bc * NN);
    const float4* ap  = (const float4*)(ws + OFF_AO + (size_t)bc * NN);

    float4 v[4];
    #pragma unroll
    for (int i = 0; i < 4; ++i) {
        float4 a0 = hp0[t + 256 * i];
        float4 a1 = hp1[t + 256 * i];
        float4 hv;
        hv.x = (a0.x + a1.x + cb) * sc + bi;
        hv.y = (a0.y + a1.y + cb) * sc + bi;
        hv.z = (a0.z + a1.z + cb) * sc + bi;
        hv.w = (a0.w + a1.w + cb) * sc + bi;
        if (g != 0.f) {
            float4 av = ap[t + 256 * i];
            hv.x += g * av.x; hv.y += g * av.y; hv.z += g * av.z; hv.w += g * av.w;
        }
        v[i] = hv;
    }

    float s1 = 0.f, s2 = 0.f;
    #pragma unroll
    for (int i = 0; i < 4; ++i) {
        s1 += v[i].x + v[i].y + v[i].z + v[i].w;
        s2 += v[i].x * v[i].x + v[i].y * v[i].y + v[i].z * v[i].z + v[i].w * v[i].w;
    }
    #pragma unroll
    for (int off = 32; off; off >>= 1) {
        s1 += __shfl_xor(s1, off);
        s2 += __shfl_xor(s2, off);
    }
    __shared__ float r1[4], r2[4];
    if ((t & 63) == 0) { r1[t >> 6] = s1; r2[t >> 6] = s2; }
    __syncthreads();
    const float S1 = r1[0] + r1[1] + r1[2] + r1[3];
    const float S2 = r2[0] + r2[1] + r2[2] + r2[3];
    const float mu  = S1 * (1.f / 4096.f);
    const float var = S2 * (1.f / 4096.f) - mu * mu;
    const float rs  = 1.f / sqrtf(var + EPSV);

    float4* op = (float4*)out + (size_t)bc * (NN / 4);
    #pragma unroll
    for (int i = 0; i < 4; ++i) {
        float4 o;
        o.x = (v[i].x - mu) * rs; o.x = o.x >= 0.f ? o.x : 0.2f * o.x;
        o.y = (v[i].y - mu) * rs; o.y = o.y >= 0.f ? o.y : 0.2f * o.y;
        o.z = (v[i].z - mu) * rs; o.z = o.z >= 0.f ? o.z : 0.2f * o.z;
        o.w = (v[i].w - mu) * rs; o.w = o.w >= 0.f ? o.w : 0.2f * o.w;
        op[t + 256 * i] = o;
    }
}

// ---------------------------------------------------------------------------
extern "C" void kernel_launch(void* const* d_in, const int* in_sizes, int n_in,
                              void* d_out, int out_size, void* d_ws, size_t ws_size,
                              hipStream_t stream) {
    const float* x      = (const float*)d_in[0];
    const float* style  = (const float*)d_in[1];
    const float* conv_w = (const float*)d_in[2];
    const float* conv_b = (const float*)d_in[3];
    const float* ss_w   = (const float*)d_in[4];
    const float* ss_b   = (const float*)d_in[5];
    const float* sb_w   = (const float*)d_in[6];
    const float* sb_b   = (const float*)d_in[7];
    const float* q_w    = (const float*)d_in[8];
    const float* q_b    = (const float*)d_in[9];
    const float* k_w    = (const float*)d_in[10];
    const float* k_b    = (const float*)d_in[11];
    const float* v_w    = (const float*)d_in[12];
    const float* v_b    = (const float*)d_in[13];
    const float* gamma  = (const float*)d_in[14];
    float* ws  = (float*)d_ws;
    float* out = (float*)d_out;

    prep<<<800, 256, 0, stream>>>(x, conv_w, style, ss_w, ss_b, sb_w, sb_b, ws);
    mfma_conv<<<dim3(64, 4, 2), 256, 0, stream>>>(ws);
    qkv_kernel<<<dim3(160, 4), 256, 0, stream>>>(ws, conv_b, q_w, q_b, k_w, k_b, v_w, v_b, gamma);
    attn_kernel<<<dim3(64, 4), 256, 0, stream>>>(ws, gamma);
    inorm_lrelu<<<512, 256, 0, stream>>>(ws, conv_b, gamma, out);
}